// Round 1
// baseline (45.619 us; speedup 1.0000x reference)
//
#include <hip/hip_runtime.h>

// out[row, j] = x[row, j] * sum_i x[row, i], rows = 128*1024, D = 256 (f32)
// One wave (64 lanes) per row; lane l owns float4 at offset l*4.

__global__ __launch_bounds__(256) void product_layer_kernel(
    const float* __restrict__ x, float* __restrict__ out, int nrows) {
    const int lane      = threadIdx.x & 63;
    const int wave_in_b = threadIdx.x >> 6;                 // 0..3
    const int waves_per_grid = (gridDim.x * blockDim.x) >> 6;
    int row = blockIdx.x * (blockDim.x >> 6) + wave_in_b;

    for (; row < nrows; row += waves_per_grid) {
        const size_t base = (size_t)row * 256;
        const float4 v = reinterpret_cast<const float4*>(x + base)[lane];

        float s = v.x + v.y + v.z + v.w;
        // full 64-lane butterfly reduction
        s += __shfl_xor(s, 32, 64);
        s += __shfl_xor(s, 16, 64);
        s += __shfl_xor(s,  8, 64);
        s += __shfl_xor(s,  4, 64);
        s += __shfl_xor(s,  2, 64);
        s += __shfl_xor(s,  1, 64);

        float4 o;
        o.x = v.x * s;
        o.y = v.y * s;
        o.z = v.z * s;
        o.w = v.w * s;
        reinterpret_cast<float4*>(out + base)[lane] = o;
    }
}

extern "C" void kernel_launch(void* const* d_in, const int* in_sizes, int n_in,
                              void* d_out, int out_size, void* d_ws, size_t ws_size,
                              hipStream_t stream) {
    const float* x = (const float*)d_in[0];
    float* out = (float*)d_out;
    const int nrows = in_sizes[0] / 256;   // 128*1024 = 131072 rows of D=256

    const int block = 256;                  // 4 waves/block
    int grid = 2048;                        // grid-stride over rows
    product_layer_kernel<<<grid, block, 0, stream>>>(x, out, nrows);
}

// Round 3
// 44.776 us; speedup vs baseline: 1.0188x; 1.0188x over previous
//
#include <hip/hip_runtime.h>

// out[row, j] = x[row, j] * sum_i x[row, i], rows = 128*1024, D = 256 (f32)
// One wave (64 lanes) per row; lane l owns 16 B at offset l*16.
// - Non-temporal stores (output never re-read) -> keep the 134 MB input
//   resident in the 256 MiB Infinity Cache across graph replays.
// - 2-row unroll per wave iteration: two independent shuffle-reduce chains.
// Native ext_vector float4: __builtin_nontemporal_store rejects HIP_vector_type.
typedef float v4f __attribute__((ext_vector_type(4)));

__global__ __launch_bounds__(256) void product_layer_kernel(
    const float* __restrict__ x, float* __restrict__ out, int nrows) {
    const int lane      = threadIdx.x & 63;
    const int wave_in_b = threadIdx.x >> 6;                   // 0..3
    const int waves     = (gridDim.x * blockDim.x) >> 6;
    int row = (blockIdx.x * (blockDim.x >> 6) + wave_in_b) * 2;
    const int stride = waves * 2;

    for (; row + 1 < nrows; row += stride) {
        const size_t base0 = (size_t)row * 256;
        const size_t base1 = base0 + 256;
        const v4f v0 = reinterpret_cast<const v4f*>(x + base0)[lane];
        const v4f v1 = reinterpret_cast<const v4f*>(x + base1)[lane];

        float s0 = v0.x + v0.y + v0.z + v0.w;
        float s1 = v1.x + v1.y + v1.z + v1.w;
        // two independent 64-lane butterflies (compiler interleaves)
        s0 += __shfl_xor(s0, 32, 64);  s1 += __shfl_xor(s1, 32, 64);
        s0 += __shfl_xor(s0, 16, 64);  s1 += __shfl_xor(s1, 16, 64);
        s0 += __shfl_xor(s0,  8, 64);  s1 += __shfl_xor(s1,  8, 64);
        s0 += __shfl_xor(s0,  4, 64);  s1 += __shfl_xor(s1,  4, 64);
        s0 += __shfl_xor(s0,  2, 64);  s1 += __shfl_xor(s1,  2, 64);
        s0 += __shfl_xor(s0,  1, 64);  s1 += __shfl_xor(s1,  1, 64);

        const v4f o0 = v0 * s0;
        const v4f o1 = v1 * s1;
        __builtin_nontemporal_store(o0, reinterpret_cast<v4f*>(out + base0) + lane);
        __builtin_nontemporal_store(o1, reinterpret_cast<v4f*>(out + base1) + lane);
    }

    // generic tail (nrows is even here, but keep correct for any nrows)
    if ((nrows & 1) && row == nrows - 1) {
        const size_t base = (size_t)row * 256;
        const v4f v = reinterpret_cast<const v4f*>(x + base)[lane];
        float s = v.x + v.y + v.z + v.w;
        s += __shfl_xor(s, 32, 64);
        s += __shfl_xor(s, 16, 64);
        s += __shfl_xor(s,  8, 64);
        s += __shfl_xor(s,  4, 64);
        s += __shfl_xor(s,  2, 64);
        s += __shfl_xor(s,  1, 64);
        const v4f o = v * s;
        __builtin_nontemporal_store(o, reinterpret_cast<v4f*>(out + base) + lane);
    }
}

extern "C" void kernel_launch(void* const* d_in, const int* in_sizes, int n_in,
                              void* d_out, int out_size, void* d_ws, size_t ws_size,
                              hipStream_t stream) {
    const float* x = (const float*)d_in[0];
    float* out = (float*)d_out;
    const int nrows = in_sizes[0] / 256;   // 128*1024 = 131072 rows of D=256

    const int block = 256;                  // 4 waves/block
    const int grid = 2048;                  // grid-stride over rows
    product_layer_kernel<<<grid, block, 0, stream>>>(x, out, nrows);
}

// Round 4
// 43.738 us; speedup vs baseline: 1.0430x; 1.0237x over previous
//
#include <hip/hip_runtime.h>

// out[row, j] = x[row, j] * sum_i x[row, i], rows = 128*1024, D = 256 (f32)
// One wave (64 lanes) per row-group of 4; lane l owns 16 B at offset l*16 of
// each row. All 4 loads issue upfront (4 outstanding HBM reads/lane -> MLP),
// then 4 independent 6-step shuffle reductions, then 4 non-temporal stores
// (output never re-read; keeps input L3-resident across graph replays).
// No grid-stride loop: exact grid, zero ramp, zero loop-carried serialization.
typedef float v4f __attribute__((ext_vector_type(4)));

__device__ __forceinline__ float wave_sum(float s) {
    s += __shfl_xor(s, 32, 64);
    s += __shfl_xor(s, 16, 64);
    s += __shfl_xor(s,  8, 64);
    s += __shfl_xor(s,  4, 64);
    s += __shfl_xor(s,  2, 64);
    s += __shfl_xor(s,  1, 64);
    return s;
}

__global__ __launch_bounds__(256) void product_layer_kernel(
    const float* __restrict__ x, float* __restrict__ out, int nrows) {
    const int lane      = threadIdx.x & 63;
    const int wave_in_b = threadIdx.x >> 6;                    // 0..3
    // each wave owns 4 consecutive rows
    const int row0 = (blockIdx.x * 4 + wave_in_b) * 4;
    if (row0 + 3 >= nrows) {
        // generic tail (not hit for 131072 rows with exact grid)
        for (int r = row0; r < nrows; ++r) {
            const size_t base = (size_t)r * 256;
            const v4f v = reinterpret_cast<const v4f*>(x + base)[lane];
            const float s = wave_sum(v.x + v.y + v.z + v.w);
            __builtin_nontemporal_store(v * s, reinterpret_cast<v4f*>(out + base) + lane);
        }
        return;
    }

    const size_t base = (size_t)row0 * 256;
    const v4f* xin = reinterpret_cast<const v4f*>(x + base);
    // 4 independent loads issue back-to-back (no deps between them)
    const v4f v0 = xin[lane];
    const v4f v1 = xin[lane + 64];
    const v4f v2 = xin[lane + 128];
    const v4f v3 = xin[lane + 192];

    float s0 = v0.x + v0.y + v0.z + v0.w;
    float s1 = v1.x + v1.y + v1.z + v1.w;
    float s2 = v2.x + v2.y + v2.z + v2.w;
    float s3 = v3.x + v3.y + v3.z + v3.w;
    // 4 independent butterflies interleave; chain latency hidden by ILP+TLP
    s0 += __shfl_xor(s0, 32, 64);  s1 += __shfl_xor(s1, 32, 64);
    s2 += __shfl_xor(s2, 32, 64);  s3 += __shfl_xor(s3, 32, 64);
    s0 += __shfl_xor(s0, 16, 64);  s1 += __shfl_xor(s1, 16, 64);
    s2 += __shfl_xor(s2, 16, 64);  s3 += __shfl_xor(s3, 16, 64);
    s0 += __shfl_xor(s0,  8, 64);  s1 += __shfl_xor(s1,  8, 64);
    s2 += __shfl_xor(s2,  8, 64);  s3 += __shfl_xor(s3,  8, 64);
    s0 += __shfl_xor(s0,  4, 64);  s1 += __shfl_xor(s1,  4, 64);
    s2 += __shfl_xor(s2,  4, 64);  s3 += __shfl_xor(s3,  4, 64);
    s0 += __shfl_xor(s0,  2, 64);  s1 += __shfl_xor(s1,  2, 64);
    s2 += __shfl_xor(s2,  2, 64);  s3 += __shfl_xor(s3,  2, 64);
    s0 += __shfl_xor(s0,  1, 64);  s1 += __shfl_xor(s1,  1, 64);
    s2 += __shfl_xor(s2,  1, 64);  s3 += __shfl_xor(s3,  1, 64);

    v4f* o = reinterpret_cast<v4f*>(out + base);
    __builtin_nontemporal_store(v0 * s0, o + lane);
    __builtin_nontemporal_store(v1 * s1, o + lane + 64);
    __builtin_nontemporal_store(v2 * s2, o + lane + 128);
    __builtin_nontemporal_store(v3 * s3, o + lane + 192);
}

extern "C" void kernel_launch(void* const* d_in, const int* in_sizes, int n_in,
                              void* d_out, int out_size, void* d_ws, size_t ws_size,
                              hipStream_t stream) {
    const float* x = (const float*)d_in[0];
    float* out = (float*)d_out;
    const int nrows = in_sizes[0] / 256;     // 131072 rows of D=256

    const int block = 256;                    // 4 waves/block, 4 rows/wave
    const int grid = (nrows + 15) / 16;       // 8192 blocks, exact for 131072
    product_layer_kernel<<<grid, block, 0, stream>>>(x, out, nrows);
}